// Round 1
// baseline (137.014 us; speedup 1.0000x reference)
//
#include <hip/hip_runtime.h>
#include <hip/hip_cooperative_groups.h>

namespace cg = cooperative_groups;

// TripletLoss semi-hard, B=512, D=256, fp32 — single cooperative kernel.
// Phase 1 (pd tiles): 256 blocks (16x16 grid of 32x32 tiles), 256 thr.
//   Stage A-rows/B-rows [32][256] in LDS (stride 260 floats -> 2-way-max bank
//   aliasing, free). Thread computes 2x2 outputs; per 4 k-steps = 4 ds_read_b128
//   + 16 FMA. sq-norms from global in parallel with staging. Epilogue: pd =
//   max(sq_r+sq_c-2*dot,0), diag zeroed, LDS-transposed coalesced float4 stores.
// grid.sync() (+ device fences for cross-XCD L2 visibility) replaces the old
//   kernel boundary — saves one graph dispatch node.
// Phase 2 (mining): waves 0-1 of each block, one anchor per wave (j=2*blk+wid).
//   pd row + labels in registers (8/lane); semi-hard min via ballot over
//   positives + shuffle broadcast + 64-lane butterfly min. Block partials ->
//   device atomicAdd; last block (ticket) computes loss = sum/count.
// Fallback: if cooperative launch is rejected, run the proven 2-kernel path.

#define BN 512
#define DF4 64

__device__ inline float wave_max64(float v){
  #pragma unroll
  for (int o = 32; o > 0; o >>= 1) v = fmaxf(v, __shfl_xor(v, o));
  return v;
}
__device__ inline float wave_min64(float v){
  #pragma unroll
  for (int o = 32; o > 0; o >>= 1) v = fminf(v, __shfl_xor(v, o));
  return v;
}

// ---------------- fused cooperative kernel ----------------
__global__ __launch_bounds__(256) void triplet_fused(
    const float* __restrict__ emb, const int* __restrict__ labels,
    float* __restrict__ pd, float* __restrict__ acc, float* __restrict__ out)
{
  __shared__ float As[32][260];   // stride 260: banks (4r+4k)%32, 2-way max (free)
  __shared__ float Bs[32][260];
  __shared__ float sqA[32], sqB[32];
  __shared__ float outt[32][36];  // store-transpose staging, 16B-aligned rows
  __shared__ float wls[2], wcs[2];

  const int t  = threadIdx.x;
  const int bi = blockIdx.x & 15, bj = blockIdx.x >> 4;
  const int R0 = bi * 32, C0 = bj * 32;
  const float4* ef4 = reinterpret_cast<const float4*>(emb);

  if (blockIdx.x == 0 && t == 0){ acc[0] = 0.f; acc[1] = 0.f; ((int*)acc)[2] = 0; }

  // stage both tiles, coalesced 1KB/instr
  #pragma unroll
  for (int j = 0; j < 8; ++j){
    int idx = t + j * 256;
    int r = idx >> 6, c = idx & 63;
    float4 va = ef4[(R0 + r) * DF4 + c];
    float4 vb = ef4[(C0 + r) * DF4 + c];
    *(float4*)&As[r][c * 4] = va;
    *(float4*)&Bs[r][c * 4] = vb;
  }
  // sq norms straight from global (L2-hot), overlaps staging latency
  {
    int half = t >> 7, u = t & 127;
    int r = u >> 2, part = u & 3;
    int base = ((half ? C0 : R0) + r) * DF4 + part * 16;
    float s = 0.f;
    #pragma unroll
    for (int i = 0; i < 16; ++i){
      float4 v = ef4[base + i];
      s += v.x*v.x + v.y*v.y + v.z*v.z + v.w*v.w;
    }
    s += __shfl_xor(s, 1); s += __shfl_xor(s, 2);
    if (part == 0){ if (half) sqB[r] = s; else sqA[r] = s; }
  }
  __syncthreads();

  const int r0 = t & 15, r1 = r0 + 16;
  const int c0 = t >> 4, c1 = c0 + 16;
  float a00 = 0.f, a01 = 0.f, a10 = 0.f, a11 = 0.f;
  #pragma unroll 8
  for (int kg = 0; kg < 64; ++kg){
    float4 A0 = *(const float4*)&As[r0][kg * 4];
    float4 A1 = *(const float4*)&As[r1][kg * 4];
    float4 B0 = *(const float4*)&Bs[c0][kg * 4];
    float4 B1 = *(const float4*)&Bs[c1][kg * 4];
    a00 += A0.x*B0.x + A0.y*B0.y + A0.z*B0.z + A0.w*B0.w;
    a01 += A0.x*B1.x + A0.y*B1.y + A0.z*B1.z + A0.w*B1.w;
    a10 += A1.x*B0.x + A1.y*B0.y + A1.z*B0.z + A1.w*B0.w;
    a11 += A1.x*B1.x + A1.y*B1.y + A1.z*B1.z + A1.w*B1.w;
  }

  const float sr0 = sqA[r0], sr1 = sqA[r1];
  const float sc0 = sqB[c0], sc1 = sqB[c1];
  float p00 = fmaxf(sr0 + sc0 - 2.f * a00, 0.f);
  float p01 = fmaxf(sr0 + sc1 - 2.f * a01, 0.f);
  float p10 = fmaxf(sr1 + sc0 - 2.f * a10, 0.f);
  float p11 = fmaxf(sr1 + sc1 - 2.f * a11, 0.f);
  if (bi == bj){                       // zero the diagonal (reference semantics)
    if (r0 == c0) p00 = 0.f;
    if (r0 == c1) p01 = 0.f;
    if (r1 == c0) p10 = 0.f;
    if (r1 == c1) p11 = 0.f;
  }
  outt[r0][c0] = p00; outt[r0][c1] = p01;
  outt[r1][c0] = p10; outt[r1][c1] = p11;
  __syncthreads();

  int rr = t >> 3, cc = t & 7;         // coalesced float4 stores, 128B/row-seg
  float4 v = *(float4*)&outt[rr][cc * 4];
  *(float4*)&pd[(R0 + rr) * BN + C0 + cc * 4] = v;

  // ---- kernel-boundary replacement: flush writer L2, grid barrier, invalidate reader caches
  __threadfence();
  cg::this_grid().sync();
  __threadfence();

  // ---- phase 2: mining, anchors j = 2*block + wid (waves 0,1)
  const int lane = t & 63, wid = t >> 6;
  if (wid < 2){
    const int j  = blockIdx.x * 2 + wid;
    const int lj = labels[j];

    const float4* prow = reinterpret_cast<const float4*>(pd + (size_t)j * BN);
    const int4*   lrow = reinterpret_cast<const int4*>(labels);
    float4 p0 = prow[lane * 2], p1 = prow[lane * 2 + 1];
    int4   l0 = lrow[lane * 2], l1 = lrow[lane * 2 + 1];
    float pk[8] = {p0.x, p0.y, p0.z, p0.w, p1.x, p1.y, p1.z, p1.w};
    int   lk[8] = {l0.x, l0.y, l0.z, l0.w, l1.x, l1.y, l1.z, l1.w};
    const int kbase = lane * 8;

    // negatives_inside: max over adj_not (rowmin filler == 0 since diag is 0)
    float ninside = 0.f;
    #pragma unroll
    for (int m = 0; m < 8; ++m)
      if (lk[m] != lj) ninside = fmaxf(ninside, pk[m]);
    ninside = wave_max64(ninside);

    float lsum = 0.f; int pcnt = 0;
    #pragma unroll
    for (int m = 0; m < 8; ++m){
      unsigned long long bal = __ballot(lk[m] == lj && (kbase + m) != j);
      while (bal){
        int L = (int)__ffsll((unsigned long long)bal) - 1;
        bal &= bal - 1;
        float tiv = __shfl(pk[m], L);             // pd[j][i], broadcast
        float vmin = 3.402823466e38f;
        #pragma unroll
        for (int mm = 0; mm < 8; ++mm)
          if (lk[mm] != lj && pk[mm] > tiv) vmin = fminf(vmin, pk[mm]);
        vmin = wave_min64(vmin);
        float semi = (vmin < 3.0e38f) ? vmin : ninside;  // mask_final fallback
        lsum += fmaxf(1.0f + tiv - semi, 0.f);
        ++pcnt;                                   // identical on all lanes
      }
    }
    if (lane == 0){ wls[wid] = lsum; wcs[wid] = (float)pcnt; }
  }
  __syncthreads();
  if (t == 0){
    float bl = wls[0] + wls[1];
    float bc = wcs[0] + wcs[1];
    atomicAdd(&acc[0], bl);
    atomicAdd(&acc[1], bc);
    __threadfence();
    int tk = atomicAdd((int*)acc + 2, 1);
    if (tk == 255){                             // last block finalizes
      __threadfence();
      float tot = atomicAdd(&acc[0], 0.f);      // device-scope coherent read
      float cnt = atomicAdd(&acc[1], 0.f);
      out[0] = tot / cnt;
    }
  }
}

// ---------------- fallback path (proven 2-kernel version) ----------------
__global__ __launch_bounds__(256) void pd_gemm(
    const float* __restrict__ emb, float* __restrict__ pd, float* __restrict__ acc)
{
  __shared__ float As[32][260];
  __shared__ float Bs[32][260];
  __shared__ float sqA[32], sqB[32];
  __shared__ float outt[32][36];

  const int t  = threadIdx.x;
  const int bi = blockIdx.x & 15, bj = blockIdx.x >> 4;
  const int R0 = bi * 32, C0 = bj * 32;
  const float4* ef4 = reinterpret_cast<const float4*>(emb);

  if (blockIdx.x == 0 && t == 0){ acc[0] = 0.f; acc[1] = 0.f; ((int*)acc)[2] = 0; }

  #pragma unroll
  for (int j = 0; j < 8; ++j){
    int idx = t + j * 256;
    int r = idx >> 6, c = idx & 63;
    float4 va = ef4[(R0 + r) * DF4 + c];
    float4 vb = ef4[(C0 + r) * DF4 + c];
    *(float4*)&As[r][c * 4] = va;
    *(float4*)&Bs[r][c * 4] = vb;
  }
  {
    int half = t >> 7, u = t & 127;
    int r = u >> 2, part = u & 3;
    int base = ((half ? C0 : R0) + r) * DF4 + part * 16;
    float s = 0.f;
    #pragma unroll
    for (int i = 0; i < 16; ++i){
      float4 v = ef4[base + i];
      s += v.x*v.x + v.y*v.y + v.z*v.z + v.w*v.w;
    }
    s += __shfl_xor(s, 1); s += __shfl_xor(s, 2);
    if (part == 0){ if (half) sqB[r] = s; else sqA[r] = s; }
  }
  __syncthreads();

  const int r0 = t & 15, r1 = r0 + 16;
  const int c0 = t >> 4, c1 = c0 + 16;
  float a00 = 0.f, a01 = 0.f, a10 = 0.f, a11 = 0.f;
  #pragma unroll 8
  for (int kg = 0; kg < 64; ++kg){
    float4 A0 = *(const float4*)&As[r0][kg * 4];
    float4 A1 = *(const float4*)&As[r1][kg * 4];
    float4 B0 = *(const float4*)&Bs[c0][kg * 4];
    float4 B1 = *(const float4*)&Bs[c1][kg * 4];
    a00 += A0.x*B0.x + A0.y*B0.y + A0.z*B0.z + A0.w*B0.w;
    a01 += A0.x*B1.x + A0.y*B1.y + A0.z*B1.z + A0.w*B1.w;
    a10 += A1.x*B0.x + A1.y*B0.y + A1.z*B0.z + A1.w*B0.w;
    a11 += A1.x*B1.x + A1.y*B1.y + A1.z*B1.z + A1.w*B1.w;
  }

  const float sr0 = sqA[r0], sr1 = sqA[r1];
  const float sc0 = sqB[c0], sc1 = sqB[c1];
  float p00 = fmaxf(sr0 + sc0 - 2.f * a00, 0.f);
  float p01 = fmaxf(sr0 + sc1 - 2.f * a01, 0.f);
  float p10 = fmaxf(sr1 + sc0 - 2.f * a10, 0.f);
  float p11 = fmaxf(sr1 + sc1 - 2.f * a11, 0.f);
  if (bi == bj){
    if (r0 == c0) p00 = 0.f;
    if (r0 == c1) p01 = 0.f;
    if (r1 == c0) p10 = 0.f;
    if (r1 == c1) p11 = 0.f;
  }
  outt[r0][c0] = p00; outt[r0][c1] = p01;
  outt[r1][c0] = p10; outt[r1][c1] = p11;
  __syncthreads();

  int rr = t >> 3, cc = t & 7;
  float4 v = *(float4*)&outt[rr][cc * 4];
  *(float4*)&pd[(R0 + rr) * BN + C0 + cc * 4] = v;
}

__global__ __launch_bounds__(256) void mining(
    const float* __restrict__ pd, const int* __restrict__ labels,
    float* __restrict__ acc, float* __restrict__ out)
{
  __shared__ float wls[4], wcs[4];
  const int t = threadIdx.x, lane = t & 63, wid = t >> 6;
  const int j  = blockIdx.x * 4 + wid;
  const int lj = labels[j];

  const float4* prow = reinterpret_cast<const float4*>(pd + (size_t)j * BN);
  const int4*   lrow = reinterpret_cast<const int4*>(labels);
  float4 p0 = prow[lane * 2], p1 = prow[lane * 2 + 1];
  int4   l0 = lrow[lane * 2], l1 = lrow[lane * 2 + 1];
  float pk[8] = {p0.x, p0.y, p0.z, p0.w, p1.x, p1.y, p1.z, p1.w};
  int   lk[8] = {l0.x, l0.y, l0.z, l0.w, l1.x, l1.y, l1.z, l1.w};
  const int kbase = lane * 8;

  float ninside = 0.f;
  #pragma unroll
  for (int m = 0; m < 8; ++m)
    if (lk[m] != lj) ninside = fmaxf(ninside, pk[m]);
  ninside = wave_max64(ninside);

  float lsum = 0.f; int pcnt = 0;
  #pragma unroll
  for (int m = 0; m < 8; ++m){
    unsigned long long bal = __ballot(lk[m] == lj && (kbase + m) != j);
    while (bal){
      int L = (int)__ffsll((unsigned long long)bal) - 1;
      bal &= bal - 1;
      float tiv = __shfl(pk[m], L);
      float vmin = 3.402823466e38f;
      #pragma unroll
      for (int mm = 0; mm < 8; ++mm)
        if (lk[mm] != lj && pk[mm] > tiv) vmin = fminf(vmin, pk[mm]);
      vmin = wave_min64(vmin);
      float semi = (vmin < 3.0e38f) ? vmin : ninside;
      lsum += fmaxf(1.0f + tiv - semi, 0.f);
      ++pcnt;
    }
  }

  if (lane == 0){ wls[wid] = lsum; wcs[wid] = (float)pcnt; }
  __syncthreads();
  if (t == 0){
    float bl = wls[0] + wls[1] + wls[2] + wls[3];
    float bc = wcs[0] + wcs[1] + wcs[2] + wcs[3];
    atomicAdd(&acc[0], bl);
    atomicAdd(&acc[1], bc);
    __threadfence();
    int tk = atomicAdd((int*)acc + 2, 1);
    if (tk == 127){
      __threadfence();
      float tot = atomicAdd(&acc[0], 0.f);
      float cnt = atomicAdd(&acc[1], 0.f);
      out[0] = tot / cnt;
    }
  }
}

extern "C" void kernel_launch(void* const* d_in, const int* in_sizes, int n_in,
                              void* d_out, int out_size, void* d_ws, size_t ws_size,
                              hipStream_t stream) {
  const float* emb    = (const float*)d_in[0];
  const int*   labels = (const int*)d_in[1];
  float* out = (float*)d_out;
  float* pdw = (float*)d_ws;                 // [512*512] pd matrix
  float* acc = pdw + BN * BN;                // [0]=loss, [1]=count, [2]=ticket

  void* args[5] = { (void*)&emb, (void*)&labels, (void*)&pdw, (void*)&acc, (void*)&out };
  hipError_t e = hipLaunchCooperativeKernel((const void*)triplet_fused,
                                            dim3(256), dim3(256), args, 0, stream);
  if (e != hipSuccess){
    // cooperative launch unavailable (e.g. capture-unsupported): proven 2-kernel path
    pd_gemm<<<256, 256, 0, stream>>>(emb, pdw, acc);
    mining<<<128, 256, 0, stream>>>(pdw, labels, acc, out);
  }
}

// Round 2
// 104.112 us; speedup vs baseline: 1.3160x; 1.3160x over previous
//
#include <hip/hip_runtime.h>

// TripletLoss semi-hard, B=512, D=256, fp32 — single fused kernel with a
// hand-rolled atomic grid barrier (cg::this_grid().sync() measured ~55-60us
// of idle spin on gfx950 — round 1 post-mortem; custom barrier ~2-3us).
//
// Phase 1 (pd tiles): 256 blocks (16x16 grid of 32x32 tiles), 256 thr.
//   Stage A-rows/B-rows [32][256] in LDS (stride 260 floats -> 2-way-max bank
//   aliasing, free). Thread computes 2x2 outputs; per 4 k-steps = 4 ds_read_b128
//   + 16 FMA. sq-norms from global in parallel with staging. Epilogue: pd =
//   max(sq_r+sq_c-2*dot,0), diag zeroed, LDS-transposed coalesced float4 stores.
// Grid barrier: monotonic device-global epoch counter (never reset ->
//   workspace-poison-proof, graph-replay-proof). Release fence before arrive,
//   acquire fence after wait (pattern validated by round-1 passing).
//   Co-residency guaranteed: 256 blocks / 256 CUs, capacity 2 blocks/CU.
// Phase 2 (mining): waves 0-1 of each block, one anchor per wave (j=2*blk+wid).
//   pd row + labels in registers (8/lane); semi-hard min via ballot over
//   positives + shuffle broadcast + 64-lane butterfly min. Block partials ->
//   device atomicAdd; last block (ticket) computes loss = sum/count.

#define BN 512
#define DF4 64

__device__ unsigned int g_bar = 0;   // monotonic epoch counter, module lifetime

__device__ inline float wave_max64(float v){
  #pragma unroll
  for (int o = 32; o > 0; o >>= 1) v = fmaxf(v, __shfl_xor(v, o));
  return v;
}
__device__ inline float wave_min64(float v){
  #pragma unroll
  for (int o = 32; o > 0; o >>= 1) v = fminf(v, __shfl_xor(v, o));
  return v;
}

__global__ __launch_bounds__(256) void triplet_fused(
    const float* __restrict__ emb, const int* __restrict__ labels,
    float* __restrict__ pd, float* __restrict__ acc, float* __restrict__ out)
{
  __shared__ float As[32][260];   // stride 260: banks (4r+4k)%32, 2-way max (free)
  __shared__ float Bs[32][260];
  __shared__ float sqA[32], sqB[32];
  __shared__ float outt[32][36];  // store-transpose staging, 16B-aligned rows
  __shared__ float wls[2], wcs[2];

  const int t  = threadIdx.x;
  const int bi = blockIdx.x & 15, bj = blockIdx.x >> 4;
  const int R0 = bi * 32, C0 = bj * 32;
  const float4* ef4 = reinterpret_cast<const float4*>(emb);

  // reset ws accumulators; published by the pre-arrive release fence below,
  // and only consumed after the grid barrier -> race-free.
  if (blockIdx.x == 0 && t == 0){ acc[0] = 0.f; acc[1] = 0.f; ((int*)acc)[2] = 0; }

  // stage both tiles, coalesced 1KB/instr
  #pragma unroll
  for (int j = 0; j < 8; ++j){
    int idx = t + j * 256;
    int r = idx >> 6, c = idx & 63;
    float4 va = ef4[(R0 + r) * DF4 + c];
    float4 vb = ef4[(C0 + r) * DF4 + c];
    *(float4*)&As[r][c * 4] = va;
    *(float4*)&Bs[r][c * 4] = vb;
  }
  // sq norms straight from global (L2-hot), overlaps staging latency
  {
    int half = t >> 7, u = t & 127;
    int r = u >> 2, part = u & 3;
    int base = ((half ? C0 : R0) + r) * DF4 + part * 16;
    float s = 0.f;
    #pragma unroll
    for (int i = 0; i < 16; ++i){
      float4 v = ef4[base + i];
      s += v.x*v.x + v.y*v.y + v.z*v.z + v.w*v.w;
    }
    s += __shfl_xor(s, 1); s += __shfl_xor(s, 2);
    if (part == 0){ if (half) sqB[r] = s; else sqA[r] = s; }
  }
  __syncthreads();

  const int r0 = t & 15, r1 = r0 + 16;
  const int c0 = t >> 4, c1 = c0 + 16;
  float a00 = 0.f, a01 = 0.f, a10 = 0.f, a11 = 0.f;
  #pragma unroll 8
  for (int kg = 0; kg < 64; ++kg){
    float4 A0 = *(const float4*)&As[r0][kg * 4];
    float4 A1 = *(const float4*)&As[r1][kg * 4];
    float4 B0 = *(const float4*)&Bs[c0][kg * 4];
    float4 B1 = *(const float4*)&Bs[c1][kg * 4];
    a00 += A0.x*B0.x + A0.y*B0.y + A0.z*B0.z + A0.w*B0.w;
    a01 += A0.x*B1.x + A0.y*B1.y + A0.z*B1.z + A0.w*B1.w;
    a10 += A1.x*B0.x + A1.y*B0.y + A1.z*B0.z + A1.w*B0.w;
    a11 += A1.x*B1.x + A1.y*B1.y + A1.z*B1.z + A1.w*B1.w;
  }

  const float sr0 = sqA[r0], sr1 = sqA[r1];
  const float sc0 = sqB[c0], sc1 = sqB[c1];
  float p00 = fmaxf(sr0 + sc0 - 2.f * a00, 0.f);
  float p01 = fmaxf(sr0 + sc1 - 2.f * a01, 0.f);
  float p10 = fmaxf(sr1 + sc0 - 2.f * a10, 0.f);
  float p11 = fmaxf(sr1 + sc1 - 2.f * a11, 0.f);
  if (bi == bj){                       // zero the diagonal (reference semantics)
    if (r0 == c0) p00 = 0.f;
    if (r0 == c1) p01 = 0.f;
    if (r1 == c0) p10 = 0.f;
    if (r1 == c1) p11 = 0.f;
  }
  outt[r0][c0] = p00; outt[r0][c1] = p01;
  outt[r1][c0] = p10; outt[r1][c1] = p11;
  __syncthreads();

  int rr = t >> 3, cc = t & 7;         // coalesced float4 stores, 128B/row-seg
  float4 v = *(float4*)&outt[rr][cc * 4];
  *(float4*)&pd[(R0 + rr) * BN + C0 + cc * 4] = v;

  // ---- custom grid barrier (replaces kernel boundary / cg::sync) ----
  __syncthreads();                     // all pd stores issued block-wide
  if (t == 0){
    __threadfence();                   // release: publish pd tile + acc reset
    unsigned old = atomicAdd(&g_bar, 1u);
    unsigned target = ((old >> 8) + 1u) << 8;   // this iteration completes at next multiple of 256
    while (__hip_atomic_load(&g_bar, __ATOMIC_RELAXED, __HIP_MEMORY_SCOPE_AGENT) < target)
      __builtin_amdgcn_s_sleep(1);
  }
  __syncthreads();
  __threadfence();                     // acquire: no stale cached pd lines

  // ---- phase 2: mining, anchors j = 2*block + wid (waves 0,1)
  const int lane = t & 63, wid = t >> 6;
  if (wid < 2){
    const int j  = blockIdx.x * 2 + wid;
    const int lj = labels[j];

    const float4* prow = reinterpret_cast<const float4*>(pd + (size_t)j * BN);
    const int4*   lrow = reinterpret_cast<const int4*>(labels);
    float4 p0 = prow[lane * 2], p1 = prow[lane * 2 + 1];
    int4   l0 = lrow[lane * 2], l1 = lrow[lane * 2 + 1];
    float pk[8] = {p0.x, p0.y, p0.z, p0.w, p1.x, p1.y, p1.z, p1.w};
    int   lk[8] = {l0.x, l0.y, l0.z, l0.w, l1.x, l1.y, l1.z, l1.w};
    const int kbase = lane * 8;

    // negatives_inside: max over adj_not (rowmin filler == 0 since diag is 0)
    float ninside = 0.f;
    #pragma unroll
    for (int m = 0; m < 8; ++m)
      if (lk[m] != lj) ninside = fmaxf(ninside, pk[m]);
    ninside = wave_max64(ninside);

    float lsum = 0.f; int pcnt = 0;
    #pragma unroll
    for (int m = 0; m < 8; ++m){
      unsigned long long bal = __ballot(lk[m] == lj && (kbase + m) != j);
      while (bal){
        int L = (int)__ffsll((unsigned long long)bal) - 1;
        bal &= bal - 1;
        float tiv = __shfl(pk[m], L);             // pd[j][i], broadcast
        float vmin = 3.402823466e38f;
        #pragma unroll
        for (int mm = 0; mm < 8; ++mm)
          if (lk[mm] != lj && pk[mm] > tiv) vmin = fminf(vmin, pk[mm]);
        vmin = wave_min64(vmin);
        float semi = (vmin < 3.0e38f) ? vmin : ninside;  // mask_final fallback
        lsum += fmaxf(1.0f + tiv - semi, 0.f);
        ++pcnt;                                   // identical on all lanes
      }
    }
    if (lane == 0){ wls[wid] = lsum; wcs[wid] = (float)pcnt; }
  }
  __syncthreads();
  if (t == 0){
    float bl = wls[0] + wls[1];
    float bc = wcs[0] + wcs[1];
    atomicAdd(&acc[0], bl);
    atomicAdd(&acc[1], bc);
    __threadfence();
    int tk = atomicAdd((int*)acc + 2, 1);
    if (tk == 255){                             // last block finalizes
      __threadfence();
      float tot = atomicAdd(&acc[0], 0.f);      // device-scope coherent read
      float cnt = atomicAdd(&acc[1], 0.f);
      out[0] = tot / cnt;
    }
  }
}

extern "C" void kernel_launch(void* const* d_in, const int* in_sizes, int n_in,
                              void* d_out, int out_size, void* d_ws, size_t ws_size,
                              hipStream_t stream) {
  const float* emb    = (const float*)d_in[0];
  const int*   labels = (const int*)d_in[1];
  float* out = (float*)d_out;
  float* pdw = (float*)d_ws;                 // [512*512] pd matrix
  float* acc = pdw + BN * BN;                // [0]=loss, [1]=count, [2]=ticket

  triplet_fused<<<256, 256, 0, stream>>>(emb, labels, pdw, acc, out);
}

// Round 3
// 69.613 us; speedup vs baseline: 1.9682x; 1.4956x over previous
//
#include <hip/hip_runtime.h>

// TripletLoss semi-hard, B=512, D=256, fp32 — fully fused, ZERO inter-block
// dependencies (rounds 1-2 showed any grid-barrier pattern costs ~50us on
// gfx950: cg::sync ~60us, custom atomic barrier + threadfence ~50us).
//
// Structure: 256 blocks x 512 thr. Block b owns anchors j0=2b, j1=2b+1 and
// computes d(j,k) for all k=0..511 directly from emb (no pd matrix, no
// barrier). Total FMA identical to the full pairwise GEMM (each row once).
// emb (512KB) is L2-resident; per-block read = 512KB -> 128MB aggregate from
// L2 (~3.7us at 34.5 TB/s). Per wave: lanes = (kr = lane>>3 -> 8 rows,
// sub = lane&7 -> 32-float slice); a load instr touches 8 rows x 128B
// contiguous = 16 lines (minimum). e_j slices held in 64 VGPRs. Slice
// partial dots reduced over the 8-lane group (3 shfl_xor), written to LDS.
// Mining (proven register-ballot form) on waves 0-1 reads d-rows from LDS.
// Loss: per-block partials via relaxed agent-scope (sc1) stores +
// s_waitcnt vmcnt(0) + monotonic fetch_add; 256th arriver finalizes with
// sc1 loads (bypass stale L2). No __threadfence anywhere.

#define BN 512
#define DF4 64   // float4s per embedding row (256 floats)

__device__ unsigned int g_fin = 0;   // monotonic completion counter (module lifetime)

__device__ inline float wave_max64(float v){
  #pragma unroll
  for (int o = 32; o > 0; o >>= 1) v = fmaxf(v, __shfl_xor(v, o));
  return v;
}
__device__ inline float wave_min64(float v){
  #pragma unroll
  for (int o = 32; o > 0; o >>= 1) v = fminf(v, __shfl_xor(v, o));
  return v;
}
__device__ inline float wave_sum64(float v){
  #pragma unroll
  for (int o = 32; o > 0; o >>= 1) v += __shfl_xor(v, o);
  return v;
}
__device__ inline float grp8_sum(float v){
  v += __shfl_xor(v, 1);
  v += __shfl_xor(v, 2);
  v += __shfl_xor(v, 4);
  return v;
}

__global__ __launch_bounds__(512) void triplet_rows(
    const float* __restrict__ emb, const int* __restrict__ labels,
    float* __restrict__ partials, float* __restrict__ out)
{
  __shared__ float dotm[2][BN];   // dot(e_j, e_k) for the block's 2 anchors
  __shared__ float sqs[BN];       // |e_k|^2
  __shared__ float wls[2], wcs[2];
  __shared__ float fs[8], fc[8];
  __shared__ int sh_fin;

  const int t = threadIdx.x, lane = t & 63, wid = t >> 6;
  const int b = blockIdx.x;
  const int j0 = 2 * b, j1 = 2 * b + 1;
  const int sub = lane & 7, kr = lane >> 3;
  const float4* ef4 = reinterpret_cast<const float4*>(emb);

  // per-lane e_j slices (32 floats per anchor), constant across passes.
  // lanes with equal sub read identical addresses -> broadcast-friendly.
  float4 ejA[8], ejB[8];
  #pragma unroll
  for (int i = 0; i < 8; ++i){
    ejA[i] = ef4[j0 * DF4 + i * 8 + sub];
    ejB[i] = ef4[j1 * DF4 + i * 8 + sub];
  }

  // 8 passes; per pass each wave covers 8 k-rows (64 rows/block-pass).
  #pragma unroll 2
  for (int pass = 0; pass < 8; ++pass){
    const int k = pass * 64 + wid * 8 + kr;
    const float4* row = ef4 + (size_t)k * DF4;
    float a0 = 0.f, a1 = 0.f, b0 = 0.f, b1 = 0.f, s0 = 0.f, s1 = 0.f;
    #pragma unroll
    for (int i = 0; i < 8; i += 2){
      float4 e0 = row[i * 8 + sub];          // 8-lane groups: 128B contiguous
      float4 e1 = row[(i + 1) * 8 + sub];
      a0 += e0.x*ejA[i].x + e0.y*ejA[i].y + e0.z*ejA[i].z + e0.w*ejA[i].w;
      b0 += e0.x*ejB[i].x + e0.y*ejB[i].y + e0.z*ejB[i].z + e0.w*ejB[i].w;
      s0 += e0.x*e0.x + e0.y*e0.y + e0.z*e0.z + e0.w*e0.w;
      a1 += e1.x*ejA[i+1].x + e1.y*ejA[i+1].y + e1.z*ejA[i+1].z + e1.w*ejA[i+1].w;
      b1 += e1.x*ejB[i+1].x + e1.y*ejB[i+1].y + e1.z*ejB[i+1].z + e1.w*ejB[i+1].w;
      s1 += e1.x*e1.x + e1.y*e1.y + e1.z*e1.z + e1.w*e1.w;
    }
    float da = grp8_sum(a0 + a1);
    float db = grp8_sum(b0 + b1);
    float ds = grp8_sum(s0 + s1);
    if (sub == 0){ dotm[0][k] = da; dotm[1][k] = db; sqs[k] = ds; }
  }
  __syncthreads();

  // ---- mining: wave w (0,1) -> anchor j0+w; d-row assembled from LDS ----
  if (wid < 2){
    const int j  = 2 * b + wid;
    const int lj = labels[j];
    const float sqj = sqs[j];

    const float4* dr   = reinterpret_cast<const float4*>(&dotm[wid][0]);
    const float4* sr   = reinterpret_cast<const float4*>(&sqs[0]);
    const int4*   lrow = reinterpret_cast<const int4*>(labels);
    float4 d0 = dr[lane * 2], d1 = dr[lane * 2 + 1];
    float4 q0 = sr[lane * 2], q1 = sr[lane * 2 + 1];
    int4   l0 = lrow[lane * 2], l1 = lrow[lane * 2 + 1];
    float dk[8] = {d0.x, d0.y, d0.z, d0.w, d1.x, d1.y, d1.z, d1.w};
    float qk[8] = {q0.x, q0.y, q0.z, q0.w, q1.x, q1.y, q1.z, q1.w};
    int   lk[8] = {l0.x, l0.y, l0.z, l0.w, l1.x, l1.y, l1.z, l1.w};
    const int kbase = lane * 8;

    float pk[8];
    #pragma unroll
    for (int m = 0; m < 8; ++m){
      float v = fmaxf(sqj + qk[m] - 2.f * dk[m], 0.f);
      pk[m] = (kbase + m == j) ? 0.f : v;     // zero diagonal (ref semantics)
    }

    // negatives_inside: max over adj_not (rowmin filler == 0 since diag is 0)
    float ninside = 0.f;
    #pragma unroll
    for (int m = 0; m < 8; ++m)
      if (lk[m] != lj) ninside = fmaxf(ninside, pk[m]);
    ninside = wave_max64(ninside);

    float lsum = 0.f; int pcnt = 0;
    #pragma unroll
    for (int m = 0; m < 8; ++m){
      unsigned long long bal = __ballot(lk[m] == lj && (kbase + m) != j);
      while (bal){
        int L = (int)__ffsll((unsigned long long)bal) - 1;
        bal &= bal - 1;
        float tiv = __shfl(pk[m], L);             // pd[j][i], broadcast
        float vmin = 3.402823466e38f;
        #pragma unroll
        for (int mm = 0; mm < 8; ++mm)
          if (lk[mm] != lj && pk[mm] > tiv) vmin = fminf(vmin, pk[mm]);
        vmin = wave_min64(vmin);
        float semi = (vmin < 3.0e38f) ? vmin : ninside;  // mask_final fallback
        lsum += fmaxf(1.0f + tiv - semi, 0.f);
        ++pcnt;                                   // identical on all lanes
      }
    }
    if (lane == 0){ wls[wid] = lsum; wcs[wid] = (float)pcnt; }
  }
  __syncthreads();

  // ---- publish block partial; last arriver (monotonic ticket) finalizes ----
  if (t == 0){
    float bl = wls[0] + wls[1];
    float bc = wcs[0] + wcs[1];
    __hip_atomic_store(&partials[2 * b],     bl, __ATOMIC_RELAXED, __HIP_MEMORY_SCOPE_AGENT);
    __hip_atomic_store(&partials[2 * b + 1], bc, __ATOMIC_RELAXED, __HIP_MEMORY_SCOPE_AGENT);
    asm volatile("s_waitcnt vmcnt(0)" ::: "memory");   // sc1 stores at coherence point
    unsigned old = __hip_atomic_fetch_add(&g_fin, 1u, __ATOMIC_RELAXED, __HIP_MEMORY_SCOPE_AGENT);
    sh_fin = ((old & 255u) == 255u) ? 1 : 0;
  }
  __syncthreads();

  if (sh_fin){                                   // block-uniform branch
    float s = 0.f, c = 0.f;
    if (t < 256){
      s = __hip_atomic_load(&partials[2 * t],     __ATOMIC_RELAXED, __HIP_MEMORY_SCOPE_AGENT);
      c = __hip_atomic_load(&partials[2 * t + 1], __ATOMIC_RELAXED, __HIP_MEMORY_SCOPE_AGENT);
    }
    s = wave_sum64(s); c = wave_sum64(c);
    if (lane == 0){ fs[wid] = s; fc[wid] = c; }
    __syncthreads();
    if (t == 0){
      float S = 0.f, C = 0.f;
      #pragma unroll
      for (int w = 0; w < 8; ++w){ S += fs[w]; C += fc[w]; }
      out[0] = S / C;                            // end-of-kernel flush publishes
    }
  }
}

extern "C" void kernel_launch(void* const* d_in, const int* in_sizes, int n_in,
                              void* d_out, int out_size, void* d_ws, size_t ws_size,
                              hipStream_t stream) {
  const float* emb    = (const float*)d_in[0];
  const int*   labels = (const int*)d_in[1];
  float* out      = (float*)d_out;
  float* partials = (float*)d_ws;              // [512] (sum,count) per block

  triplet_rows<<<256, 512, 0, stream>>>(emb, labels, partials, out);
}